// Round 10
// baseline (138.096 us; speedup 1.0000x reference)
//
#include <hip/hip_runtime.h>

typedef _Float16 f16;
typedef _Float16 f16x4 __attribute__((ext_vector_type(4)));
typedef _Float16 f16x8 __attribute__((ext_vector_type(8)));
typedef float    f32x4 __attribute__((ext_vector_type(4)));

#define S2C 2.88539008177792681472f   // 2*log2(e)

// ws layout, f16-element offsets
#define OFF_STF  0u          // states A-frags [10][256 rg2][2 rt][2 ks][64 lane][8]  5242880
#define OFF_AC   5242880u    // action f16 compact [8192][10][16]                     1310720
#define OFF_WEF  6553600u    // W_edge B-frags [90][4 ks][8 cg][64 lane][8]           1474560
#define OFF_WNF  8028160u    // W_node B-frags K-permuted [10][7 ks][4 c][64 lane][8]  143360
#define OFF_BE2  8171520u    // f32: be2[11520], bn2[640]; then 8 f16 zeros
#define OFF_Z    8195840u    // 8 f16 zeros (pad source for action kstep)

__device__ __forceinline__ float fast_exp2(float x){
#if __has_builtin(__builtin_amdgcn_exp2f)
    return __builtin_amdgcn_exp2f(x);
#else
    return exp2f(x);
#endif
}
__device__ __forceinline__ float fast_rcp(float x){
#if __has_builtin(__builtin_amdgcn_rcpf)
    return __builtin_amdgcn_rcpf(x);
#else
    return 1.0f/x;
#endif
}

#define MFMA16(a,b,c) __builtin_amdgcn_mfma_f32_16x16x32_f16(a,b,c,0,0,0)

// ---------------- prologue: cvt + fragment-order + bias scale (unchanged) ----------------
__global__ void prep(const float* __restrict__ st, const float* __restrict__ ac,
                     const float* __restrict__ We, const float* __restrict__ be,
                     const float* __restrict__ Wn, const float* __restrict__ bn,
                     f16* __restrict__ ws16){
    const int bid = blockIdx.x, t = threadIdx.x;
    if (bid < 2560){                                   // states -> A-fragment order
        int g = bid*256 + t;                           // [node][rg2][rt][ks][lane]
        int lane = g&63, ks = (g>>6)&1, rt = (g>>7)&1, rg2 = (g>>8)&255, node = g>>16;
        int row = rg2*32 + rt*16 + (lane&15);
        int k   = ks*32 + (lane>>4)*8;
        const float* src = st + ((size_t)row*10 + node)*64 + k;
        const float4 v0 = *(const float4*)src;
        const float4 v1 = *(const float4*)(src+4);
        f16x8 h; h[0]=(f16)v0.x; h[1]=(f16)v0.y; h[2]=(f16)v0.z; h[3]=(f16)v0.w;
                 h[4]=(f16)v1.x; h[5]=(f16)v1.y; h[6]=(f16)v1.z; h[7]=(f16)v1.w;
        *(f16x8*)(ws16 + OFF_STF + (size_t)g*8) = h;
    } else if (bid < 3840){                            // action f32 -> f16 compact
        int g = (bid-2560)*256 + t;                    // 327680 float4s
        const float4 v = ((const float4*)ac)[g];
        f16x4 h; h[0]=(f16)v.x; h[1]=(f16)v.y; h[2]=(f16)v.z; h[3]=(f16)v.w;
        *(f16x4*)(ws16 + OFF_AC + (size_t)g*4) = h;
    } else if (bid < 4560){                            // W_edge -> B-fragment order
        int g = (bid-3840)*256 + t;                    // < 184320
        int l = g & 15, q = (g>>4)&3, cg = (g>>6)&7, ks = (g>>9)&3, e = g>>11;
        const float* src = We + e*16384 + (ks*32 + q*8)*128 + cg*16 + l;
        f16x8 h;
        #pragma unroll
        for (int u=0;u<8;u++) h[u] = (f16)src[u*128];
        *(f16x8*)(ws16 + OFF_WEF + (size_t)g*8) = h;
    } else if (bid < 4630){                            // W_node -> B-frags, K-permuted
        int g = (bid-4560)*256 + t;                    // < 17920
        if (g < 17920){
            int l = g&15, q=(g>>4)&3, c=(g>>6)&3, r=g>>8;
            int ks2 = r % 7, kn = r / 7;
            f16x8 h;
            #pragma unroll
            for (int u=0;u<8;u++){
                int knew = ks2*32 + q*8 + u;
                // K-order: [agg 0..127 -> f=knew+80][states/action 128..207 -> f=knew-128][pad]
                int f = (knew < 128) ? (knew + 80) : (knew - 128);
                h[u] = (knew < 208) ? (f16)Wn[kn*13312 + f*64 + c*16 + l] : (f16)0.0f;
            }
            *(f16x8*)(ws16 + OFF_WNF + (size_t)kn*14336 + ((size_t)(ks2*4+c)*64 + q*16 + l)*8) = h;
        }
    } else {                                           // biases * 2log2e, zero pad
        int g = (bid-4630)*256 + t;
        float* be2 = (float*)(ws16 + OFF_BE2);
        if (g < 11520)      be2[g] = S2C*be[g];
        else if (g < 12160) be2[g] = S2C*bn[g-11520];
        else if (g < 12168) ws16[OFF_Z + (g-12160)] = (f16)0.0f;
    }
}

// ---------------- main kernel: register double-buffer pipeline, ILP-scheduled ----------------
// amdgpu_waves_per_eu(2,2) caps occupancy at 2 waves/EU so the scheduler has NO
// incentive to compress register pressure: the explicit prefetch buffers can live
// in the full 256-VGPR budget and all 20 next-edge loads stay in flight behind
// the current edge's MFMA+tanh block.
__launch_bounds__(128)
__attribute__((amdgpu_waves_per_eu(2, 2)))
__global__ void gnn_main(const f16* __restrict__ ws16, float* __restrict__ out){
    __shared__ alignas(16) f16 sAgg[32*128];           // 8 KB

    const f16* stf = ws16 + OFF_STF;
    const f16* Wef = ws16 + OFF_WEF;
    const float* be2 = (const float*)(ws16 + OFF_BE2);
    const float* bn2 = be2 + 11520;

    const int t = threadIdx.x, lane = t&63, wid = t>>6;   // wid in {0,1}
    const int l15 = lane&15, q = lane>>4, qo = q<<3;
    const int i  = blockIdx.x >> 8;                    // node 0..9
    const int rb = blockIdx.x & 255;                   // 32-row group 0..255
    const int b0 = rb*32;
    const int cs = wid;                                // H column half
    const int e0 = 9*i;

    // double-buffered operand registers
    f16x8 ajb[2][4];
    f16x8 bfb[2][4][4];

    // prologue: issue edge-0 loads first, then ai (independent, also in flight)
    {
        const int j0 = (i==0) ? 1 : 0;
        const f16* p = stf + (size_t)(j0*256 + rb)*2048 + lane*8;
        #pragma unroll
        for (int r=0; r<4; ++r) ajb[0][r] = *(const f16x8*)(p + r*512);
        const f16* wb = Wef + (size_t)(e0*32 + cs*4)*512 + lane*8;
        #pragma unroll
        for (int ks4=0; ks4<4; ++ks4)
            #pragma unroll
            for (int c=0; c<4; ++c)
                bfb[0][ks4][c] = *(const f16x8*)(wb + (ks4*8 + c)*512);
    }
    f16x8 ai[4];
    {
        const f16* p = stf + (size_t)(i*256 + rb)*2048 + lane*8;
        ai[0] = *(const f16x8*)p;        ai[1] = *(const f16x8*)(p+512);
        ai[2] = *(const f16x8*)(p+1024); ai[3] = *(const f16x8*)(p+1536);
    }

    f32x4 agg[2][4] = {};

    #pragma unroll
    for (int e=0; e<9; ++e){
        const int cur = e&1, nxt = cur^1;
        const int ebase = e0 + e;

        // ---- prefetch edge e+1 into the alternate buffer (no consumer here) ----
        if (e < 8){
            const int j2 = (e+1) + ((e+1) >= i);
            const f16* p = stf + (size_t)(j2*256 + rb)*2048 + lane*8;
            #pragma unroll
            for (int r=0; r<4; ++r) ajb[nxt][r] = *(const f16x8*)(p + r*512);
            const f16* wb = Wef + (size_t)((ebase+1)*32 + cs*4)*512 + lane*8;
            #pragma unroll
            for (int ks4=0; ks4<4; ++ks4)
                #pragma unroll
                for (int c=0; c<4; ++c)
                    bfb[nxt][ks4][c] = *(const f16x8*)(wb + (ks4*8 + c)*512);
        }
        float bv[4];
        #pragma unroll
        for (int c=0; c<4; ++c) bv[c] = be2[ebase*128 + cs*64 + c*16 + l15];

        // ---- compute on the CURRENT buffer, one row-tile at a time (msg = 16 VGPR) ----
        #pragma unroll
        for (int rt=0; rt<2; ++rt){
            f32x4 msg[4] = {};
            #pragma unroll
            for (int ks4=0; ks4<4; ++ks4){
                f16x8 a = (ks4 < 2) ? ai[rt*2 + ks4] : ajb[cur][rt*2 + (ks4-2)];
                #pragma unroll
                for (int c=0; c<4; ++c)
                    msg[c] = MFMA16(a, bfb[cur][ks4][c], msg[c]);
            }
            // tanh + aggregate: sum tanh = 9 - 2*sum rcp(exp2(S2C*x+b2)+1)
            #pragma unroll
            for (int c=0; c<4; ++c)
                #pragma unroll
                for (int r2=0; r2<4; ++r2){
                    float tt = __builtin_fmaf(msg[c][r2], S2C, bv[c]);
                    float rr = fast_rcp(fast_exp2(tt) + 1.0f);
                    agg[rt][c][r2] = __builtin_fmaf(-2.0f, rr, agg[rt][c][r2]);
                }
        }
    }

    // ---- agg (C-layout) -> sAgg f16 (A-layout, swizzled), +9 fold; ONE barrier ----
    #pragma unroll
    for (int rt=0; rt<2; ++rt)
        #pragma unroll
        for (int c=0; c<4; ++c)
            #pragma unroll
            for (int r2=0; r2<4; ++r2){
                int lrow = rt*16 + q*4 + r2;           // 0..31
                int col  = cs*64 + c*16 + l15;         // 0..127
                sAgg[lrow*128 + (((col>>3) ^ (lrow&7))<<3) + (col&7)] = (f16)(agg[rt][c][r2] + 9.0f);
            }
    __syncthreads();

    // ---- stage 2: out = tanh([agg|states|action] @ Wn_perm[i] + bn) ; wave = 16 rows ----
    f32x4 acc[4] = {};
    const f16* wnb = ws16 + OFF_WNF + (size_t)i*14336;
    const f16* acp = ws16 + OFF_AC;
    const f16* zb  = ws16 + OFF_Z;
    #pragma unroll
    for (int ks2=0; ks2<7; ++ks2){
        f16x8 a;
        if (ks2 < 4){                                  // agg region (K 0..127)
            int lrow = wid*16 + l15;
            a = *(const f16x8*)(sAgg + lrow*128 + (((ks2*4 + q) ^ (l15&7))<<3));
        } else if (ks2 < 6){                           // states region (K 128..191)
            a = *(const f16x8*)(stf + (size_t)(i*256 + rb)*2048 + wid*1024 + (ks2-4)*512 + lane*8);
        } else {                                       // action (K 192..207) + zero pad
            int row = b0 + wid*16 + l15;
            const f16* ap = (q < 2) ? (acp + ((size_t)row*10 + i)*16 + qo) : zb;
            a = *(const f16x8*)ap;
        }
        f16x8 bf[4];
        #pragma unroll
        for (int c=0; c<4; ++c)
            bf[c] = *(const f16x8*)(wnb + (size_t)(ks2*4+c)*512 + lane*8);
        #pragma unroll
        for (int c=0; c<4; ++c)
            acc[c] = MFMA16(a, bf[c], acc[c]);
    }
    float bnv[4];
    #pragma unroll
    for (int c=0; c<4; ++c) bnv[c] = bn2[i*64 + c*16 + l15];
    #pragma unroll
    for (int c=0; c<4; ++c)
        #pragma unroll
        for (int r2=0; r2<4; ++r2){
            int row = b0 + wid*16 + q*4 + r2;
            int col = c*16 + l15;
            float tt = __builtin_fmaf(acc[c][r2], S2C, bnv[c]);
            float rr = fast_rcp(fast_exp2(tt) + 1.0f);
            out[((size_t)row*10 + i)*64 + col] = __builtin_fmaf(-2.0f, rr, 1.0f);
        }
}

extern "C" void kernel_launch(void* const* d_in, const int* in_sizes, int n_in,
                              void* d_out, int out_size, void* d_ws, size_t ws_size,
                              hipStream_t stream) {
    const float* states = (const float*)d_in[0];
    const float* action = (const float*)d_in[1];
    const float* W_edge = (const float*)d_in[2];
    const float* b_edge = (const float*)d_in[3];
    const float* W_node = (const float*)d_in[4];
    const float* b_node = (const float*)d_in[5];
    f16* ws16 = (f16*)d_ws;   // ~16.4 MB used

    hipLaunchKernelGGL(prep, dim3(4678), dim3(256), 0, stream,
                       states, action, W_edge, b_edge, W_node, b_node, ws16);
    hipLaunchKernelGGL(gnn_main, dim3(2560), dim3(128), 0, stream,
                       ws16, (float*)d_out);
}